// Round 5
// baseline (236.930 us; speedup 1.0000x reference)
//
#include <hip/hip_runtime.h>

#define SEQ  256
#define DIM  20
#define NCLS 5

typedef float v2f __attribute__((ext_vector_type(2)));

// quad_perm DPP: xor1 = [1,0,3,2] -> 0xB1, xor2 = [2,3,0,1] -> 0x4E
#define DPPF(v, ctrl) \
    __int_as_float(__builtin_amdgcn_mov_dpp(__float_as_int(v), (ctrl), 0xF, 0xF, false))

__device__ __forceinline__ float fast_tanh(float x) {
    // tanh(x) = 1 - 2/(exp(2x)+1); exp(2x) = exp2(x * 2*log2e)
    float e2x = __builtin_amdgcn_exp2f(x * 2.8853900817779268f);
    float r   = __builtin_amdgcn_rcpf(e2x + 1.0f);
    return fmaf(-2.0f, r, 1.0f);
}

// 4 lanes per batch row; lane kq = tid&3 owns k-slice [5kq, 5kq+5).
// Each lane computes PARTIAL dots for ALL 20 units over its 5-wide k-slice
// (weights 20u x 5k x 2 matrices = 200 floats, pinned via inline-asm loads).
// Quad butterfly (DPP, pure VALU) gives every lane all 20 full sums; tanh is
// done redundantly x4; each lane keeps its 5-slice via cndmask selects.
// ZERO DS ops and ZERO weight reloads in the 256-step loop.

// select hn[5*kq + j] with compile-time register indices
#define SELH(j) ((kq & 2) ? ((kq & 1) ? hn[15 + (j)] : hn[10 + (j)]) \
                          : ((kq & 1) ? hn[5 + (j)]  : hn[(j)]))

#define RSTEP(E0, E1, E4, F0, F1, F4, PFTOK, NIDX, NTOK)                       \
    {                                                                          \
        const float* _ep = emb + (long)(PFTOK) * DIM + k0;                     \
        float _f0 = _ep[0], _f1 = _ep[1], _f2 = _ep[2], _f3 = _ep[3],          \
              _f4 = _ep[4];                                                    \
        const float _fl = ((PFTOK) != 0) ? 1.0f : 0.0f;                        \
        NTOK = xrow[(NIDX) < SEQ ? (NIDX) : (SEQ - 1)];                        \
        float _s[20];                                                          \
        _Pragma("unroll")                                                      \
        for (int u = 0; u < 20; ++u) {                                         \
            v2f _a = E0 * wih2[u][0];                                          \
            _a = __builtin_elementwise_fma(wih2[u][1], E1, _a);                \
            _a = __builtin_elementwise_fma(whh2[u][0], hp0, _a);               \
            _a = __builtin_elementwise_fma(whh2[u][1], hp1, _a);               \
            float _t = _a.x + _a.y;                                            \
            _t = fmaf(wih4[u], E4, _t);                                        \
            _t = fmaf(whh4[u], hs, _t);                                        \
            _s[u] = _t;                                                        \
        }                                                                      \
        _Pragma("unroll")                                                      \
        for (int u = 0; u < 20; ++u) _s[u] += DPPF(_s[u], 0xB1);               \
        _Pragma("unroll")                                                      \
        for (int u = 0; u < 20; ++u) _s[u] += DPPF(_s[u], 0x4E);               \
        _Pragma("unroll")                                                      \
        for (int u = 0; u < 20; ++u) hn[u] = fast_tanh(_s[u]);                 \
        {                                                                      \
            float _h0 = SELH(0), _h1 = SELH(1), _h2 = SELH(2),                 \
                  _h3 = SELH(3), _h4 = SELH(4);                                \
            hp0 = (v2f){_h0, _h1};                                             \
            hp1 = (v2f){_h2, _h3};                                             \
            hs  = _h4;                                                         \
        }                                                                      \
        F0 = (v2f){_f0, _f1} * _fl;                                            \
        F1 = (v2f){_f2, _f3} * _fl;                                            \
        F4 = _f4 * _fl;                                                        \
    }

__global__ __launch_bounds__(256, 1)
void rnn_fused(const int* __restrict__ x,
               const float* __restrict__ emb,
               const float* __restrict__ W_ih,
               const float* __restrict__ W_hh,
               const float* __restrict__ W_cls,
               const float* __restrict__ b_cls,
               float* __restrict__ out,
               int B)
{
    const int tid = blockIdx.x * blockDim.x + threadIdx.x;
    const int row = tid >> 2;
    const int kq  = tid & 3;
    if (row >= B) return;
    const int k0 = kq * 5;

    // ---- weight slices via inline-asm loads: non-rematerializable, must
    // stay in VGPRs for all 256 steps (200 floats; 512-reg budget at 1 w/EU).
    float wih_s[20][5], whh_s[20][5];
#pragma unroll
    for (int u = 0; u < 20; ++u) {
#pragma unroll
        for (int k = 0; k < 5; ++k) {
            asm volatile("global_load_dword %0, %1, off"
                         : "=v"(wih_s[u][k]) : "v"(W_ih + u * DIM + k0 + k));
            asm volatile("global_load_dword %0, %1, off"
                         : "=v"(whh_s[u][k]) : "v"(W_hh + u * DIM + k0 + k));
        }
    }
    asm volatile("s_waitcnt vmcnt(0)" ::: "memory");
    __builtin_amdgcn_sched_barrier(0);   // nothing may float above the drain

    // pack into pairs for v_pk_fma_f32
    v2f wih2[20][2], whh2[20][2];
    float wih4[20], whh4[20];
#pragma unroll
    for (int u = 0; u < 20; ++u) {
        wih2[u][0] = (v2f){wih_s[u][0], wih_s[u][1]};
        wih2[u][1] = (v2f){wih_s[u][2], wih_s[u][3]};
        wih4[u]    = wih_s[u][4];
        whh2[u][0] = (v2f){whh_s[u][0], whh_s[u][1]};
        whh2[u][1] = (v2f){whh_s[u][2], whh_s[u][3]};
        whh4[u]    = whh_s[u][4];
    }

    const int* xrow = x + (long)row * SEQ;

    v2f hp0 = (v2f)(0.0f), hp1 = (v2f)(0.0f);
    float hs = 0.0f;
    float hn[20];
#pragma unroll
    for (int u = 0; u < 20; ++u) hn[u] = 0.0f;

    int tokA = xrow[0], tokB = xrow[1];
    v2f eA0, eA1, eB0, eB1;
    float eA4, eB4;
    {
        const float* ep = emb + (long)tokA * DIM + k0;
        const float fl = (tokA != 0) ? 1.0f : 0.0f;
        eA0 = (v2f){ep[0], ep[1]} * fl;
        eA1 = (v2f){ep[2], ep[3]} * fl;
        eA4 = ep[4] * fl;
    }

    int tokC;
#pragma unroll 1
    for (int s = 0; s < SEQ; s += 2) {
        // step s: consume eA, prefetch eB <- tokB, fetch tokC = x[s+2]
        RSTEP(eA0, eA1, eA4, eB0, eB1, eB4, tokB, s + 2, tokC)
        // step s+1: consume eB, prefetch eA <- tokC, fetch tokB = x[s+3]
        RSTEP(eB0, eB1, eB4, eA0, eA1, eA4, tokC, s + 3, tokB)
    }

    // ---- classifier: every lane has the full final h in hn[20]
    float y[NCLS];
#pragma unroll
    for (int c = 0; c < NCLS; ++c) {
        float acc = b_cls[c];
#pragma unroll
        for (int d = 0; d < DIM; ++d) acc = fmaf(W_cls[c * DIM + d], hn[d], acc);
        y[c] = acc;
    }
    if (kq == 0) {
        float* o = out + (long)row * NCLS;
        o[0] = y[0]; o[1] = y[1]; o[2] = y[2]; o[3] = y[3]; o[4] = y[4];
    }
}

extern "C" void kernel_launch(void* const* d_in, const int* in_sizes, int n_in,
                              void* d_out, int out_size, void* d_ws, size_t ws_size,
                              hipStream_t stream) {
    const int*   x     = (const int*)d_in[0];
    const float* emb   = (const float*)d_in[1];
    const float* W_ih  = (const float*)d_in[2];
    const float* W_hh  = (const float*)d_in[3];
    const float* W_cls = (const float*)d_in[4];
    const float* b_cls = (const float*)d_in[5];
    float* out = (float*)d_out;

    const int B = in_sizes[0] / SEQ;            // 16384
    const int threads = B * 4;                   // 4 lanes per row
    const int block = 256;
    const int grid = (threads + block - 1) / block;
    rnn_fused<<<grid, block, 0, stream>>>(x, emb, W_ih, W_hh, W_cls, b_cls, out, B);
}

// Round 7
// 161.051 us; speedup vs baseline: 1.4712x; 1.4712x over previous
//
#include <hip/hip_runtime.h>
#include <hip/hip_bf16.h>

#define SEQ  256
#define DIM  20
#define NCLS 5

typedef short  bf16x8 __attribute__((ext_vector_type(8)));
typedef float  f32x4  __attribute__((ext_vector_type(4)));

__device__ __forceinline__ float fast_tanh(float x) {
    // tanh(x) = 1 - 2/(exp(2x)+1); exp(2x) = exp2(x * 2*log2e)
    float e2x = __builtin_amdgcn_exp2f(x * 2.8853900817779268f);
    float r   = __builtin_amdgcn_rcpf(e2x + 1.0f);
    return fmaf(-2.0f, r, 1.0f);
}

__device__ __forceinline__ int cvt_pk_bf16(float lo, float hi) {
    int r;
    asm("v_cvt_pk_bf16_f32 %0, %1, %2" : "=v"(r) : "v"(lo), "v"(hi));
    return r;
}

union I4B { int i[4]; bf16x8 f; };

// One wave = 16 batch rows. Recurrence as MFMA (two K=32 tiles):
//   D[unit, row] = W_ih.e + W_hh.h
// Weights in 5 A-fragments (20 VGPRs). D (col=lane&15, row=4q+reg) is
// tanh'd, cvt_pk'd to bf16 pairs, and exchanged into the next B-frag
// (col=lane&15, k=8q+elem) with SIX bpermutes (pull semantics: the source
// REGISTER is read on the SOURCE lane, so W-pairs and T-pairs need separate
// instructions) + 2 cndmasks. Zero A-columns (k>=20) kill all garbage slots.
__global__ __launch_bounds__(256, 1)
void rnn_mfma(const int* __restrict__ x,
              const float* __restrict__ emb,
              const float* __restrict__ W_ih,
              const float* __restrict__ W_hh,
              const float* __restrict__ W_cls,
              const float* __restrict__ b_cls,
              float* __restrict__ out, int B)
{
    const int gtid = blockIdx.x * blockDim.x + threadIdx.x;
    const int wave = gtid >> 6;
    const int lane = (int)(threadIdx.x & 63);
    const int c = lane & 15;      // batch column of the tile
    const int q = lane >> 4;      // quadrant
    const int row0 = wave * 16;
    if (row0 >= B) return;

    // ---- A fragments: lane holds A[row=c][k=8q+j], zero outside bounds.
    auto loadA = [&](const float* M, int U0, int ROWS) {
        bf16x8 f;
        const int uu = U0 + c;
        const int ur = uu < ROWS ? uu : 0;           // clamped in-bounds addr
#pragma unroll
        for (int j = 0; j < 8; ++j) {
            const int kk = 8 * q + j;
            const int kr = kk < DIM ? kk : 0;
            float v = M[ur * DIM + kr];
            v = (uu < ROWS && kk < DIM) ? v : 0.0f;
            __hip_bfloat16 hb = __float2bfloat16(v);
            f[j] = *reinterpret_cast<short*>(&hb);
        }
        return f;
    };
    const bf16x8 A0h = loadA(W_hh,  0, DIM);   // units 0-15,  W_hh
    const bf16x8 A0e = loadA(W_ih,  0, DIM);   // units 0-15,  W_ih
    const bf16x8 A1h = loadA(W_hh, 16, DIM);   // units 16-19 (rows 4-15 zero)
    const bf16x8 A1e = loadA(W_ih, 16, DIM);
    const bf16x8 Acl = loadA(W_cls, 0, NCLS);  // classes 0-4 (rows 5-15 zero)

    float bias[4];
#pragma unroll
    for (int j = 0; j < 4; ++j) {
        const int idx = 4 * q + j;
        bias[j] = (idx < NCLS) ? b_cls[idx] : 0.0f;
    }

    // Exchange addresses (byte = src_lane*4). Destination needs:
    //  i[0],i[1]: q=0 <- (c,0).W0/W1  (h0..3)  | q=1 <- (c,2).W0/W1 (h8..11)
    //  i[2],i[3]: q=0 <- (c,1).W0/W1  (h4..7)  | q=1 <- (c,3).W0/W1 (h12..15)
    //  q=2 i[0],i[1] <- (c,0).T0/T1 (h16..19); everything else garbage->0*A
    const int aW01 = (((q == 1) ? c + 32 : c)) << 2;
    const int aW23 = (((q == 1) ? c + 48 : c + 16)) << 2;
    const int aT   = c << 2;
    const int eoff0 = (q == 0) ? 0 : (q == 1) ? 8 : 16;   // e element offsets,
    const int eoff1 = (q == 0) ? 4 : (q == 1) ? 12 : 16;  // clamped in-bounds

    const int* xp = x + (size_t)(row0 + c) * SEQ;
    const f32x4 zf = {0.0f, 0.0f, 0.0f, 0.0f};

    // ---- h0 = 0; build e-frag for step 0; prefetch token 1
    I4B Bh; Bh.i[0] = Bh.i[1] = Bh.i[2] = Bh.i[3] = 0;
    I4B Be;
    int tok1;
    {
        const int tok0 = xp[0];
        tok1 = xp[1];
        const float* ep = emb + (size_t)tok0 * DIM;
        float4 lo = *(const float4*)(ep + eoff0);
        float4 hi = *(const float4*)(ep + eoff1);
        const bool nz = (tok0 != 0);               // padding_idx = 0
        Be.i[0] = nz ? cvt_pk_bf16(lo.x, lo.y) : 0;
        Be.i[1] = nz ? cvt_pk_bf16(lo.z, lo.w) : 0;
        Be.i[2] = nz ? cvt_pk_bf16(hi.x, hi.y) : 0;
        Be.i[3] = nz ? cvt_pk_bf16(hi.z, hi.w) : 0;
    }

#pragma unroll 1
    for (int s = 0; s < SEQ; ++s) {
        // prefetch e(s+1) and token(s+2) — latency hidden under MFMA+exchange
        const float* ep = emb + (size_t)tok1 * DIM;
        float4 lo = *(const float4*)(ep + eoff0);
        float4 hi = *(const float4*)(ep + eoff1);
        const bool nz = (tok1 != 0);
        const int i2 = (s + 2 < SEQ) ? s + 2 : SEQ - 1;
        const int tok2 = xp[i2];

        // D = W_ih.e + W_hh.h
        f32x4 acc0 = __builtin_amdgcn_mfma_f32_16x16x32_bf16(A0e, Be.f, zf, 0, 0, 0);
        f32x4 acc1 = __builtin_amdgcn_mfma_f32_16x16x32_bf16(A1e, Be.f, zf, 0, 0, 0);
        acc0 = __builtin_amdgcn_mfma_f32_16x16x32_bf16(A0h, Bh.f, acc0, 0, 0, 0);
        acc1 = __builtin_amdgcn_mfma_f32_16x16x32_bf16(A1h, Bh.f, acc1, 0, 0, 0);

        // tanh (zero rows stay zero)
        const float t0 = fast_tanh(acc0[0]), t1 = fast_tanh(acc0[1]);
        const float t2 = fast_tanh(acc0[2]), t3 = fast_tanh(acc0[3]);
        const float u0 = fast_tanh(acc1[0]), u1 = fast_tanh(acc1[1]);
        const float u2 = fast_tanh(acc1[2]), u3 = fast_tanh(acc1[3]);

        // pack pairs: W0=(units 4q,4q+1), W1=(4q+2,4q+3); T0=(16,17),T1=(18,19) on q'=0
        const int W0 = cvt_pk_bf16(t0, t1);
        const int W1 = cvt_pk_bf16(t2, t3);
        const int T0 = cvt_pk_bf16(u0, u1);
        const int T1 = cvt_pk_bf16(u2, u3);

        const int v0W = __builtin_amdgcn_ds_bpermute(aW01, W0);
        const int v1W = __builtin_amdgcn_ds_bpermute(aW01, W1);
        const int v2W = __builtin_amdgcn_ds_bpermute(aW23, W0);
        const int v3W = __builtin_amdgcn_ds_bpermute(aW23, W1);
        const int v0T = __builtin_amdgcn_ds_bpermute(aT, T0);
        const int v1T = __builtin_amdgcn_ds_bpermute(aT, T1);
        const bool q2 = (q == 2);
        Bh.i[0] = q2 ? v0T : v0W;
        Bh.i[1] = q2 ? v1T : v1W;
        Bh.i[2] = v2W;
        Bh.i[3] = v3W;

        // finish e(s+1)
        Be.i[0] = nz ? cvt_pk_bf16(lo.x, lo.y) : 0;
        Be.i[1] = nz ? cvt_pk_bf16(lo.z, lo.w) : 0;
        Be.i[2] = nz ? cvt_pk_bf16(hi.x, hi.y) : 0;
        Be.i[3] = nz ? cvt_pk_bf16(hi.z, hi.w) : 0;
        tok1 = tok2;
    }

    // ---- classifier: one MFMA (classes in rows 0-4; k>=20 A-cols are zero)
    const f32x4 y = __builtin_amdgcn_mfma_f32_16x16x32_bf16(Acl, Bh.f, zf, 0, 0, 0);
    float* orow = out + (size_t)(row0 + c) * NCLS;
    if (q == 0) {          // rows 0-3 = classes 0-3 for batch row c
        orow[0] = y[0] + bias[0];
        orow[1] = y[1] + bias[1];
        orow[2] = y[2] + bias[2];
        orow[3] = y[3] + bias[3];
    } else if (q == 1) {   // row 4 = class 4
        orow[4] = y[0] + bias[0];
    }
}

extern "C" void kernel_launch(void* const* d_in, const int* in_sizes, int n_in,
                              void* d_out, int out_size, void* d_ws, size_t ws_size,
                              hipStream_t stream) {
    const int*   x     = (const int*)d_in[0];
    const float* emb   = (const float*)d_in[1];
    const float* W_ih  = (const float*)d_in[2];
    const float* W_hh  = (const float*)d_in[3];
    const float* W_cls = (const float*)d_in[4];
    const float* b_cls = (const float*)d_in[5];
    float* out = (float*)d_out;

    const int B = in_sizes[0] / SEQ;            // 16384
    const int threads = B * 4;                   // 64 lanes per 16 rows
    const int block = 256;
    const int grid = (threads + block - 1) / block;   // 1024 waves total
    rnn_mfma<<<grid, block, 0, stream>>>(x, emb, W_ih, W_hh, W_cls, b_cls, out, B);
}

// Round 9
// 160.450 us; speedup vs baseline: 1.4767x; 1.0037x over previous
//
#include <hip/hip_runtime.h>
#include <hip/hip_bf16.h>

#define SEQ  256
#define DIM  20
#define NCLS 5

typedef short  bf16x8 __attribute__((ext_vector_type(8)));
typedef float  f32x4  __attribute__((ext_vector_type(4)));

__device__ __forceinline__ float fast_tanh(float x) {
    // tanh(x) = 1 - 2/(exp(2x)+1); exp(2x) = exp2(x * 2*log2e)
    float e2x = __builtin_amdgcn_exp2f(x * 2.8853900817779268f);
    float r   = __builtin_amdgcn_rcpf(e2x + 1.0f);
    return fmaf(-2.0f, r, 1.0f);
}

__device__ __forceinline__ int cvt_pk_bf16(float lo, float hi) {
    int r;
    asm("v_cvt_pk_bf16_f32 %0, %1, %2" : "=v"(r) : "v"(lo), "v"(hi));
    return r;
}

// v_permlane32_swap_b32 a, b  (S1 semantics — established empirically by r8's
// failure, whose layout was provably correct under the alternative S2):
//   a' : lanes 0-31 = a(0-31),  lanes 32-63 = b(0-31)
//   b' : lanes 0-31 = a(32-63), lanes 32-63 = b(32-63)
// i.e. swap a's UPPER half with b's LOWER half.
__device__ __forceinline__ void pl32swap(int &a, int &b) {
    asm("v_permlane32_swap_b32 %0, %1" : "+v"(a), "+v"(b));
}

// Recurrent-contraction column permutation: A-column kappa holds unit perm(kappa).
// kappa = [0-3]->u0-3, [4-7]->u8-11, [8-11]->u4-7, [12-15]->u12-15, [16-19]->u16-19.
// Makes every D->B move pure "same lane" or "lane+/-32", so the whole
// h-exchange is TWO v_permlane32_swap_b32 (zero DS ops in the loop).
__device__ __forceinline__ int permk(int k) {
    return (k >= 4 && k < 8) ? k + 4 : (k >= 8 && k < 12) ? k - 4 : k;
}

union I4B { int i[4]; bf16x8 f; };

// One wave = 16 batch rows. Per step:
//   ae  = W_ih . e            (2 MFMAs, Be ready from prefetch -> off chain)
//   acc = W_hh . h + ae       (2 MFMAs, C-chained; ONE on the critical path)
//   h'  = tanh(acc); repack via 2 permlane32_swap into next B-frag.
// Exchange map under S1 with pl32swap(W0,T0)/pl32swap(W1,T1), per (q,slot):
//   i[0]=W0': q0=(u0,u1)  q1=(u4,u5)   q2=T0@q0=(u16,u17)  q3=junk
//   i[1]=W1': q0=(u2,u3)  q1=(u6,u7)   q2=T1@q0=(u18,u19)  q3=junk
//   i[2]=T0': q0=W0@q2=(u8,u9)   q1=W0@q3=(u12,u13)  q2+=junk
//   i[3]=T1': q0=W1@q2=(u10,u11) q1=W1@q3=(u14,u15)  q2+=junk
// Required (B row k holds h[permk(k)]): q0 k0-7 -> u0-3,u8-11; q1 k8-15 ->
// u4-7,u12-15; q2 k16-19 -> u16-19. All junk slots hit zero A-columns.
__global__ __launch_bounds__(256, 1)
void rnn_mfma(const int* __restrict__ x,
              const float* __restrict__ emb,
              const float* __restrict__ W_ih,
              const float* __restrict__ W_hh,
              const float* __restrict__ W_cls,
              const float* __restrict__ b_cls,
              float* __restrict__ out, int B)
{
    const int gtid = blockIdx.x * blockDim.x + threadIdx.x;
    const int wave = gtid >> 6;
    const int lane = (int)(threadIdx.x & 63);
    const int c = lane & 15;      // batch column of the tile
    const int q = lane >> 4;      // quadrant
    const int row0 = wave * 16;
    if (row0 >= B) return;

    // ---- A fragments: lane holds A[row=c][k=8q+j], zero outside bounds.
    auto loadA = [&](const float* M, int U0, int ROWS, bool pk) {
        bf16x8 f;
        const int uu = U0 + c;
        const int ur = uu < ROWS ? uu : 0;           // clamped in-bounds addr
#pragma unroll
        for (int j = 0; j < 8; ++j) {
            const int kk = 8 * q + j;
            const int kp = pk ? permk(kk) : kk;      // recurrent k-permutation
            const int kr = kp < DIM ? kp : 0;
            float v = M[ur * DIM + kr];
            v = (uu < ROWS && kk < DIM) ? v : 0.0f;
            __hip_bfloat16 hb = __float2bfloat16(v);
            f[j] = *reinterpret_cast<short*>(&hb);
        }
        return f;
    };
    const bf16x8 A0h = loadA(W_hh,  0, DIM,  true);   // units 0-15,  W_hh
    const bf16x8 A0e = loadA(W_ih,  0, DIM,  false);  // units 0-15,  W_ih
    const bf16x8 A1h = loadA(W_hh, 16, DIM,  true);   // units 16-19
    const bf16x8 A1e = loadA(W_ih, 16, DIM,  false);
    const bf16x8 Acl = loadA(W_cls, 0, NCLS, true);   // classes 0-4

    float bias[4];
#pragma unroll
    for (int j = 0; j < 4; ++j) {
        const int idx = 4 * q + j;
        bias[j] = (idx < NCLS) ? b_cls[idx] : 0.0f;
    }

    const int eoff0 = (q == 0) ? 0 : (q == 1) ? 8 : 16;   // e element offsets,
    const int eoff1 = (q == 0) ? 4 : (q == 1) ? 12 : 16;  // clamped in-bounds

    const int* xp = x + (size_t)(row0 + c) * SEQ;
    const f32x4 zf = {0.0f, 0.0f, 0.0f, 0.0f};

    // ---- h0 = 0; build e-frag for step 0; prefetch token 1
    I4B Bh; Bh.i[0] = Bh.i[1] = Bh.i[2] = Bh.i[3] = 0;
    I4B Be;
    int tok1;
    {
        const int tok0 = xp[0];
        tok1 = xp[1];
        const float* ep = emb + (size_t)tok0 * DIM;
        float4 lo = *(const float4*)(ep + eoff0);
        float4 hi = *(const float4*)(ep + eoff1);
        const bool nz = (tok0 != 0);               // padding_idx = 0
        Be.i[0] = nz ? cvt_pk_bf16(lo.x, lo.y) : 0;
        Be.i[1] = nz ? cvt_pk_bf16(lo.z, lo.w) : 0;
        Be.i[2] = nz ? cvt_pk_bf16(hi.x, hi.y) : 0;
        Be.i[3] = nz ? cvt_pk_bf16(hi.z, hi.w) : 0;
    }

#pragma unroll 1
    for (int s = 0; s < SEQ; ++s) {
        // prefetch e(s+1) and token(s+2) — hidden under the step
        const float* ep = emb + (size_t)tok1 * DIM;
        float4 lo = *(const float4*)(ep + eoff0);
        float4 hi = *(const float4*)(ep + eoff1);
        const bool nz = (tok1 != 0);
        const int i2 = (s + 2 < SEQ) ? s + 2 : SEQ - 1;
        const int tok2 = xp[i2];

        // e-contribution first (off the critical path), h-MFMA C-chained on top
        const f32x4 ae0 = __builtin_amdgcn_mfma_f32_16x16x32_bf16(A0e, Be.f, zf, 0, 0, 0);
        const f32x4 ae1 = __builtin_amdgcn_mfma_f32_16x16x32_bf16(A1e, Be.f, zf, 0, 0, 0);
        const f32x4 acc0 = __builtin_amdgcn_mfma_f32_16x16x32_bf16(A0h, Bh.f, ae0, 0, 0, 0);
        const f32x4 acc1 = __builtin_amdgcn_mfma_f32_16x16x32_bf16(A1h, Bh.f, ae1, 0, 0, 0);

        // tanh (zero rows stay zero)
        const float t0 = fast_tanh(acc0[0]), t1 = fast_tanh(acc0[1]);
        const float t2 = fast_tanh(acc0[2]), t3 = fast_tanh(acc0[3]);
        const float u0 = fast_tanh(acc1[0]), u1 = fast_tanh(acc1[1]);
        const float u2 = fast_tanh(acc1[2]), u3 = fast_tanh(acc1[3]);

        // pack: W0=(u 4q,4q+1), W1=(4q+2,4q+3); T0=(16,17), T1=(18,19) live on q0
        int w0 = cvt_pk_bf16(t0, t1);   // W0  (vdst of swap: keeps its low half)
        int w1 = cvt_pk_bf16(t2, t3);   // W1
        int tp0 = cvt_pk_bf16(u0, u1);  // T0  (vsrc: donates its low half)
        int tp1 = cvt_pk_bf16(u2, u3);  // T1

        // exchange: 2 VALU cross-lane swaps, zero DS.  S1:
        //   w'  = {w_low, t_low}   -> B slots i[0]/i[1]
        //   t'  = {w_high, t_high} -> B slots i[2]/i[3]
        pl32swap(w0, tp0);
        pl32swap(w1, tp1);
        Bh.i[0] = w0;
        Bh.i[1] = w1;
        Bh.i[2] = tp0;
        Bh.i[3] = tp1;

        // finish e(s+1)
        Be.i[0] = nz ? cvt_pk_bf16(lo.x, lo.y) : 0;
        Be.i[1] = nz ? cvt_pk_bf16(lo.z, lo.w) : 0;
        Be.i[2] = nz ? cvt_pk_bf16(hi.x, hi.y) : 0;
        Be.i[3] = nz ? cvt_pk_bf16(hi.z, hi.w) : 0;
        tok1 = tok2;
    }

    // ---- classifier: one MFMA (classes in rows 0-4; k-cols >= 20 are zero)
    const f32x4 y = __builtin_amdgcn_mfma_f32_16x16x32_bf16(Acl, Bh.f, zf, 0, 0, 0);
    float* orow = out + (size_t)(row0 + c) * NCLS;
    if (q == 0) {          // rows 0-3 = classes 0-3 for batch row c
        orow[0] = y[0] + bias[0];
        orow[1] = y[1] + bias[1];
        orow[2] = y[2] + bias[2];
        orow[3] = y[3] + bias[3];
    } else if (q == 1) {   // row 4 = class 4
        orow[4] = y[0] + bias[0];
    }
}

extern "C" void kernel_launch(void* const* d_in, const int* in_sizes, int n_in,
                              void* d_out, int out_size, void* d_ws, size_t ws_size,
                              hipStream_t stream) {
    const int*   x     = (const int*)d_in[0];
    const float* emb   = (const float*)d_in[1];
    const float* W_ih  = (const float*)d_in[2];
    const float* W_hh  = (const float*)d_in[3];
    const float* W_cls = (const float*)d_in[4];
    const float* b_cls = (const float*)d_in[5];
    float* out = (float*)d_out;

    const int B = in_sizes[0] / SEQ;            // 16384
    const int threads = B * 4;                   // 64 lanes per 16 rows
    const int block = 256;
    const int grid = (threads + block - 1) / block;   // 1024 waves total
    rnn_mfma<<<grid, block, 0, stream>>>(x, emb, W_ih, W_hh, W_cls, b_cls, out, B);
}

// Round 10
// 92.762 us; speedup vs baseline: 2.5542x; 1.7297x over previous
//
#include <hip/hip_runtime.h>
#include <hip/hip_bf16.h>

#define SEQ  256
#define DIM  20
#define NCLS 5

typedef short  bf16x8 __attribute__((ext_vector_type(8)));
typedef float  f32x4  __attribute__((ext_vector_type(4)));

__device__ __forceinline__ float fast_tanh(float x) {
    // tanh(x) = 1 - 2/(exp(2x)+1); exp(2x) = exp2(x * 2*log2e)
    float e2x = __builtin_amdgcn_exp2f(x * 2.8853900817779268f);
    float r   = __builtin_amdgcn_rcpf(e2x + 1.0f);
    return fmaf(-2.0f, r, 1.0f);
}

__device__ __forceinline__ int cvt_pk_bf16(float lo, float hi) {
    int r;
    asm("v_cvt_pk_bf16_f32 %0, %1, %2" : "=v"(r) : "v"(lo), "v"(hi));
    return r;
}

// v_permlane32_swap_b32 a, b  (S1 semantics, established by r8/r9 A-B result):
//   a' : lanes 0-31 = a(0-31),  lanes 32-63 = b(0-31)
//   b' : lanes 0-31 = a(32-63), lanes 32-63 = b(32-63)
__device__ __forceinline__ void pl32swap(int &a, int &b) {
    asm("v_permlane32_swap_b32 %0, %1" : "+v"(a), "+v"(b));
}

// Recurrent-contraction column permutation (A-column kappa holds unit
// perm(kappa)): [0-3]->u0-3, [4-7]->u8-11, [8-11]->u4-7, [12-15]->u12-15,
// [16-19]->u16-19. Makes the whole h-exchange 2 permlane32_swap, zero DS.
__device__ __forceinline__ int permk(int k) {
    return (k >= 4 && k < 8) ? k + 4 : (k >= 8 && k < 12) ? k - 4 : k;
}

union I4B { int i[4]; bf16x8 f; };

// One wave = 16 batch rows; 4 MFMAs per step (e-MFMAs feed h-MFMAs as C).
// DEPTH-2 EMBEDDING PREFETCH: step s issues the gather for e(s+2) and
// converts e(s+1) (issued a full iteration earlier) -> the VMEM wait at the
// convert has >= 1 step of cover; the compiler leaves the younger s+2 loads
// outstanding (counted vmcnt), so gather latency is off the critical path.
__global__ __launch_bounds__(256, 1)
void rnn_mfma(const int* __restrict__ x,
              const float* __restrict__ emb,
              const float* __restrict__ W_ih,
              const float* __restrict__ W_hh,
              const float* __restrict__ W_cls,
              const float* __restrict__ b_cls,
              float* __restrict__ out, int B)
{
    const int gtid = blockIdx.x * blockDim.x + threadIdx.x;
    const int wave = gtid >> 6;
    const int lane = (int)(threadIdx.x & 63);
    const int c = lane & 15;      // batch column of the tile
    const int q = lane >> 4;      // quadrant
    const int row0 = wave * 16;
    if (row0 >= B) return;

    // ---- A fragments: lane holds A[row=c][k=8q+j], zero outside bounds.
    auto loadA = [&](const float* M, int U0, int ROWS, bool pk) {
        bf16x8 f;
        const int uu = U0 + c;
        const int ur = uu < ROWS ? uu : 0;           // clamped in-bounds addr
#pragma unroll
        for (int j = 0; j < 8; ++j) {
            const int kk = 8 * q + j;
            const int kp = pk ? permk(kk) : kk;      // recurrent k-permutation
            const int kr = kp < DIM ? kp : 0;
            float v = M[ur * DIM + kr];
            v = (uu < ROWS && kk < DIM) ? v : 0.0f;
            __hip_bfloat16 hb = __float2bfloat16(v);
            f[j] = *reinterpret_cast<short*>(&hb);
        }
        return f;
    };
    const bf16x8 A0h = loadA(W_hh,  0, DIM,  true);   // units 0-15,  W_hh
    const bf16x8 A0e = loadA(W_ih,  0, DIM,  false);  // units 0-15,  W_ih
    const bf16x8 A1h = loadA(W_hh, 16, DIM,  true);   // units 16-19
    const bf16x8 A1e = loadA(W_ih, 16, DIM,  false);
    const bf16x8 Acl = loadA(W_cls, 0, NCLS, true);   // classes 0-4

    float bias[4];
#pragma unroll
    for (int j = 0; j < 4; ++j) {
        const int idx = 4 * q + j;
        bias[j] = (idx < NCLS) ? b_cls[idx] : 0.0f;
    }

    const int eoff0 = (q == 0) ? 0 : (q == 1) ? 8 : 16;   // e element offsets,
    const int eoff1 = (q == 0) ? 4 : (q == 1) ? 12 : 16;  // clamped in-bounds

    const int* xp = x + (size_t)(row0 + c) * SEQ;
    const f32x4 zf = {0.0f, 0.0f, 0.0f, 0.0f};

    // ---- prologue: Be(0) converted now; e(1) raw in flight; tok for s+2.
    I4B Bh; Bh.i[0] = Bh.i[1] = Bh.i[2] = Bh.i[3] = 0;
    I4B Be;
    const int tok0 = xp[0];
    const int tok1 = xp[1];
    int tokN = xp[2];                 // token consumed by the gather in iter s
    {
        const float* ep = emb + (size_t)tok0 * DIM;
        float4 lo = *(const float4*)(ep + eoff0);
        float4 hi = *(const float4*)(ep + eoff1);
        const bool nz = (tok0 != 0);  // padding_idx = 0
        Be.i[0] = nz ? cvt_pk_bf16(lo.x, lo.y) : 0;
        Be.i[1] = nz ? cvt_pk_bf16(lo.z, lo.w) : 0;
        Be.i[2] = nz ? cvt_pk_bf16(hi.x, hi.y) : 0;
        Be.i[3] = nz ? cvt_pk_bf16(hi.z, hi.w) : 0;
    }
    float4 lo1, hi1;
    bool nz1;
    {
        const float* ep = emb + (size_t)tok1 * DIM;
        lo1 = *(const float4*)(ep + eoff0);
        hi1 = *(const float4*)(ep + eoff1);
        nz1 = (tok1 != 0);
    }

#pragma unroll 1
    for (int s = 0; s < SEQ; ++s) {
        // issue gather e(s+2) + token(s+3) — consumed NEXT iteration
        const float* ep = emb + (size_t)tokN * DIM;
        const float4 lo2 = *(const float4*)(ep + eoff0);
        const float4 hi2 = *(const float4*)(ep + eoff1);
        const bool nz2 = (tokN != 0);
        const int i3 = (s + 3 < SEQ) ? s + 3 : SEQ - 1;
        const int tokNext = xp[i3];

        // e-contribution (Be ready since last iter), h-MFMA C-chained on top
        const f32x4 ae0 = __builtin_amdgcn_mfma_f32_16x16x32_bf16(A0e, Be.f, zf, 0, 0, 0);
        const f32x4 ae1 = __builtin_amdgcn_mfma_f32_16x16x32_bf16(A1e, Be.f, zf, 0, 0, 0);
        const f32x4 acc0 = __builtin_amdgcn_mfma_f32_16x16x32_bf16(A0h, Bh.f, ae0, 0, 0, 0);
        const f32x4 acc1 = __builtin_amdgcn_mfma_f32_16x16x32_bf16(A1h, Bh.f, ae1, 0, 0, 0);

        // tanh (zero rows stay zero)
        const float t0 = fast_tanh(acc0[0]), t1 = fast_tanh(acc0[1]);
        const float t2 = fast_tanh(acc0[2]), t3 = fast_tanh(acc0[3]);
        const float u0 = fast_tanh(acc1[0]), u1 = fast_tanh(acc1[1]);
        const float u2 = fast_tanh(acc1[2]), u3 = fast_tanh(acc1[3]);

        // pack + exchange (2 VALU cross-lane swaps; junk slots hit zero A-cols)
        int w0  = cvt_pk_bf16(t0, t1);
        int w1  = cvt_pk_bf16(t2, t3);
        int tp0 = cvt_pk_bf16(u0, u1);
        int tp1 = cvt_pk_bf16(u2, u3);
        pl32swap(w0, tp0);   // w' = {w_low, t_low}; t' = {w_high, t_high}
        pl32swap(w1, tp1);
        Bh.i[0] = w0;
        Bh.i[1] = w1;
        Bh.i[2] = tp0;
        Bh.i[3] = tp1;

        // convert e(s+1): loads issued LAST iteration -> full step of cover
        Be.i[0] = nz1 ? cvt_pk_bf16(lo1.x, lo1.y) : 0;
        Be.i[1] = nz1 ? cvt_pk_bf16(lo1.z, lo1.w) : 0;
        Be.i[2] = nz1 ? cvt_pk_bf16(hi1.x, hi1.y) : 0;
        Be.i[3] = nz1 ? cvt_pk_bf16(hi1.z, hi1.w) : 0;

        // rotate pipeline state
        lo1 = lo2; hi1 = hi2; nz1 = nz2; tokN = tokNext;
    }

    // ---- classifier: one MFMA (classes in rows 0-4; k-cols >= 20 are zero)
    const f32x4 y = __builtin_amdgcn_mfma_f32_16x16x32_bf16(Acl, Bh.f, zf, 0, 0, 0);
    float* orow = out + (size_t)(row0 + c) * NCLS;
    if (q == 0) {          // rows 0-3 = classes 0-3 for batch row c
        orow[0] = y[0] + bias[0];
        orow[1] = y[1] + bias[1];
        orow[2] = y[2] + bias[2];
        orow[3] = y[3] + bias[3];
    } else if (q == 1) {   // row 4 = class 4
        orow[4] = y[0] + bias[0];
    }
}

extern "C" void kernel_launch(void* const* d_in, const int* in_sizes, int n_in,
                              void* d_out, int out_size, void* d_ws, size_t ws_size,
                              hipStream_t stream) {
    const int*   x     = (const int*)d_in[0];
    const float* emb   = (const float*)d_in[1];
    const float* W_ih  = (const float*)d_in[2];
    const float* W_hh  = (const float*)d_in[3];
    const float* W_cls = (const float*)d_in[4];
    const float* b_cls = (const float*)d_in[5];
    float* out = (float*)d_out;

    const int B = in_sizes[0] / SEQ;            // 16384
    const int threads = B * 4;                   // 64 lanes per 16 rows
    const int block = 256;
    const int grid = (threads + block - 1) / block;   // 1024 waves total
    rnn_mfma<<<grid, block, 0, stream>>>(x, emb, W_ih, W_hh, W_cls, b_cls, out, B);
}